// Round 3
// baseline (557.604 us; speedup 1.0000x reference)
//
#include <hip/hip_runtime.h>
#include <stdint.h>

#define NA 200000
#define NB 8
#define NM 64
#define CPI 782                 // anchor chunks per image (782*256 = 200192)
#define NT (NB*CPI)             // 6256 tiles
#define GRID 768                // 3 blocks/CU on 256 CUs -- co-residency guaranteed
#define MAGIC 0x13579BDFu

// ---- workspace layout (dword offsets) ----
// bar: [2i]=arrive, [2i+1]=release for barrier i (0..3); [8]=init-ready flag
#define O_BAR   0
#define O_SCAL  16                    // 8 images x 16 slots: [0]np [1]nn [2]ps(f32) [3]bs(f32)
#define O_L1C   144                   // 8 x 256
#define O_L1S   (O_L1C+2048)
#define O_L2C   (O_L1S+2048)          // 8 x 4096
#define O_L2S   (O_L2C+32768)
#define O_L3C   (O_L2S+32768)
#define O_L3S   (O_L3C+32768)
#define O_KEYS  (O_L3S+32768)         // 8 x 200000
#define N_ZERO  (O_KEYS-O_SCAL)       // 135296 dwords ~ 529 KB
// total ws: (135312 + 1600000)*4 ~ 6.62 MB

__device__ __forceinline__ unsigned int f2key(float f) {
    unsigned int u = __float_as_uint(f);
    return (u & 0x80000000u) ? ~u : (u | 0x80000000u);
}
__device__ __forceinline__ float key2f(unsigned int k) {
    return (k & 0x80000000u) ? __uint_as_float(k & 0x7fffffffu) : __uint_as_float(~k);
}

// one-shot grid barrier (slots pre-zeroed in init)
__device__ __forceinline__ void gbar(unsigned int* bar, int idx, int nblk) {
    __syncthreads();
    if (threadIdx.x == 0) {
        __threadfence();   // release: drain + L2 writeback (cross-XCD visibility)
        unsigned int t = __hip_atomic_fetch_add(&bar[2*idx], 1u, __ATOMIC_RELAXED, __HIP_MEMORY_SCOPE_AGENT);
        if (t == (unsigned int)(nblk - 1)) {
            __hip_atomic_store(&bar[2*idx+1], 1u, __ATOMIC_RELAXED, __HIP_MEMORY_SCOPE_AGENT);
        } else {
            while (__hip_atomic_load(&bar[2*idx+1], __ATOMIC_RELAXED, __HIP_MEMORY_SCOPE_AGENT) == 0u)
                __builtin_amdgcn_s_sleep(2);
        }
        __threadfence();   // acquire: invalidate caches so post-barrier loads are fresh
    }
    __syncthreads();
}

// exact select over 256-bin (cnt,sum) histogram; result: crossing bin c,
// cab = count strictly above c, sab = sum strictly above c. target >= 1.
__device__ void sel256(const unsigned int* cnt, const float* sum, unsigned int target,
                       unsigned int* s_sc, float* s_ss, unsigned int* s_res, float* s_resf,
                       unsigned int* c, unsigned int* cab, float* sab) {
    const int t = threadIdx.x;
    s_sc[t] = cnt[t]; s_ss[t] = sum[t];
    __syncthreads();
    for (int d = 1; d < 256; d <<= 1) {
        unsigned int uc = (t + d < 256) ? s_sc[t + d] : 0u;
        float fs = (t + d < 256) ? s_ss[t + d] : 0.0f;
        __syncthreads();
        s_sc[t] += uc; s_ss[t] += fs;
        __syncthreads();
    }
    unsigned int nxt = (t < 255) ? s_sc[t + 1] : 0u;
    float nxs = (t < 255) ? s_ss[t + 1] : 0.0f;
    if (s_sc[t] >= target && nxt < target) { s_res[0] = (unsigned int)t; s_res[1] = nxt; *s_resf = nxs; }
    __syncthreads();
    *c = s_res[0]; *cab = s_res[1]; *sab = *s_resf;
    __syncthreads();
}

// exact select over 4096-bin global (cnt,sum) histogram
__device__ void sel4096g(const unsigned int* cnt, const float* sum, unsigned int target,
                         unsigned int* s_sc, float* s_ss, unsigned int* s_res, float* s_resf,
                         unsigned int* c, unsigned int* cab, float* sab) {
    const int t = threadIdx.x;
    unsigned int cb[16]; float sb[16];
    const uint4*  cp = (const uint4*)(cnt + t * 16);
    const float4* sp = (const float4*)(sum + t * 16);
#pragma unroll
    for (int j = 0; j < 4; ++j) {
        uint4 u = cp[j];  cb[4*j] = u.x; cb[4*j+1] = u.y; cb[4*j+2] = u.z; cb[4*j+3] = u.w;
        float4 f = sp[j]; sb[4*j] = f.x; sb[4*j+1] = f.y; sb[4*j+2] = f.z; sb[4*j+3] = f.w;
    }
    unsigned int cc = 0; float cs = 0.0f;
#pragma unroll
    for (int j = 0; j < 16; ++j) { cc += cb[j]; cs += sb[j]; }
    s_sc[t] = cc; s_ss[t] = cs;
    __syncthreads();
    for (int d = 1; d < 256; d <<= 1) {
        unsigned int uc = (t + d < 256) ? s_sc[t + d] : 0u;
        float fs = (t + d < 256) ? s_ss[t + d] : 0.0f;
        __syncthreads();
        s_sc[t] += uc; s_ss[t] += fs;
        __syncthreads();
    }
    unsigned int run = (t < 255) ? s_sc[t + 1] : 0u;
    float runs = (t < 255) ? s_ss[t + 1] : 0.0f;
#pragma unroll
    for (int j = 15; j >= 0; --j) {
        const unsigned int prev = run; const float prevs = runs;
        run += cb[j]; runs += sb[j];
        if (run >= target && prev < target) {
            s_res[0] = (unsigned int)(t * 16 + j); s_res[1] = prev; *s_resf = prevs;
        }
    }
    __syncthreads();
    *c = s_res[0]; *cab = s_res[1]; *sab = *s_resf;
    __syncthreads();
}

__global__ __launch_bounds__(256, 3) void k_all(
    const float* __restrict__ cls, const float* __restrict__ reg,
    const float* __restrict__ anchors, const float* __restrict__ ann,
    unsigned int* __restrict__ ws, float* __restrict__ out)
{
    __shared__ float4 sbox[NM];
    __shared__ float  areab[NM];
    __shared__ unsigned int hc8[256];
    __shared__ float hs8[256];
    __shared__ unsigned int s_sc[256];
    __shared__ float s_ss[256];
    __shared__ unsigned int s_res[2];
    __shared__ float s_resf;
    __shared__ unsigned int s_np, s_nn;
    __shared__ float s_ps, s_bs;
    __shared__ unsigned int sh_k[NB], sh_np[NB], sh_c1[NB], sh_cab1[NB], sh_c2[NB], sh_t2[NB], sh_cab2[NB];
    __shared__ float sh_sab1[NB], sh_sab2[NB];

    const int tid = threadIdx.x;
    const int bid = blockIdx.x;
    unsigned int* bar  = ws + O_BAR;
    unsigned int* scal = ws + O_SCAL;
    unsigned int* l1c  = ws + O_L1C;   float* l1s = (float*)(ws + O_L1S);
    unsigned int* l2c  = ws + O_L2C;   float* l2s = (float*)(ws + O_L2S);
    unsigned int* l3c  = ws + O_L3C;   float* l3s = (float*)(ws + O_L3S);
    unsigned int* keys = ws + O_KEYS;

    // ---- init: block 0 zeroes barrier slots, publishes ready; then all zero ws ----
    if (bid == 0 && tid == 0) {
        for (int j = 0; j < 8; ++j) bar[j] = 0u;
        __threadfence();
        __hip_atomic_store(&bar[8], MAGIC, __ATOMIC_RELEASE, __HIP_MEMORY_SCOPE_AGENT);
    } else if (tid == 0) {
        while (__hip_atomic_load(&bar[8], __ATOMIC_RELAXED, __HIP_MEMORY_SCOPE_AGENT) != MAGIC)
            __builtin_amdgcn_s_sleep(2);
        __threadfence();
    }
    __syncthreads();
    for (int j = bid * 256 + tid; j < N_ZERO; j += GRID * 256) ws[O_SCAL + j] = 0u;
    gbar(bar, 0, GRID);

    // ================= phase A: IoU argmax via cross-multiply (no divide), stats, keys, L1 hist =====
    for (int t = bid; t < NT; t += GRID) {
        const int b = t / CPI;
        const int chunk = t - b * CPI;
        if (tid < NM) {
            float4 bb = ((const float4*)ann)[b * NM + tid];
            if (!(bb.x > 0.0f)) {  // invalid -> inter 0, ua inf, ratio 0
                bb.x = __builtin_inff(); bb.y = __builtin_inff();
                bb.z = -__builtin_inff(); bb.w = -__builtin_inff();
            }
            sbox[tid] = bb;
            areab[tid] = (bb.z - bb.x) * (bb.w - bb.y);
        }
        hc8[tid] = 0u; hs8[tid] = 0.0f;
        if (tid == 0) { s_np = 0u; s_nn = 0u; s_ps = 0.0f; s_bs = 0.0f; }
        __syncthreads();

        const int i = chunk * 256 + tid;
        bool pos = false, neg = false;
        float posv = 0.0f, boxv = 0.0f;
        if (i < NA) {
            const float4 a4 = ((const float4*)anchors)[i];
            float bi = -1.0f, bu = 1.0f;   // best ratio as (inter, ua) pair
            int arg = 0;
            {
#pragma clang fp contract(off)
                const float area_a = (a4.z - a4.x) * (a4.w - a4.y);
#pragma unroll 4
                for (int m = 0; m < NM; ++m) {
                    const float4 bb = sbox[m];
                    const float ab = areab[m];
                    const float iw = fmaxf(fminf(a4.z, bb.z) - fmaxf(a4.x, bb.x), 0.0f);
                    const float ih = fmaxf(fminf(a4.w, bb.w) - fmaxf(a4.y, bb.y), 0.0f);
                    const float inter = iw * ih;
                    const float ua = fmaxf(area_a + ab - inter, 1e-8f);
                    if (inter * bu > bi * ua) { bi = inter; bu = ua; arg = m; }
                }
                pos = (bi >= 0.5f * bu);
                neg = (bi <  0.3f * bu);
            }
            const float2 cv = ((const float2*)cls)[(size_t)b * NA + i];
            unsigned int key = 0u;
            if (neg) {
                const float nl = -cv.y;
                key = f2key(nl);
                atomicAdd(&hc8[key >> 24], 1u);
                atomicAdd(&hs8[key >> 24], nl);
            }
            keys[(size_t)b * NA + i] = key;
            if (pos) {
                posv = -cv.x;
                const float4 g = sbox[arg];
                const float aw = a4.z - a4.x, ah = a4.w - a4.y;
                const float acx = a4.x + 0.5f * aw, acy = a4.y + 0.5f * ah;
                const float gw = g.z - g.x, gh = g.w - g.y;
                const float gcx = g.x + 0.5f * gw, gcy = g.y + 0.5f * gh;
                const float t0 = ((gcx - acx) / (aw + 1e-14f)) / 0.1f;
                const float t1 = ((gcy - acy) / (ah + 1e-14f)) / 0.1f;
                const float t2 = logf(gw / aw) / 0.2f;
                const float t3 = logf(gh / ah) / 0.2f;
                const float4 r = ((const float4*)reg)[(size_t)b * NA + i];
                const float d0 = fabsf(t0 - r.x);
                const float d1 = fabsf(t1 - r.y);
                const float d2 = fabsf(t2 - r.z);
                const float d3 = fabsf(t3 - r.w);
                const float l0 = (d0 < 1.0f) ? 0.5f * d0 * d0 : d0 - 0.5f;
                const float l1 = (d1 < 1.0f) ? 0.5f * d1 * d1 : d1 - 0.5f;
                const float l2 = (d2 < 1.0f) ? 0.5f * d2 * d2 : d2 - 0.5f;
                const float l3 = (d3 < 1.0f) ? 0.5f * d3 * d3 : d3 - 0.5f;
                boxv = l0 + l1 + l2 + l3;
            }
        }
        const unsigned long long pb = __ballot(pos);
        const unsigned long long nb = __ballot(neg);
        if (pb) {
            for (int off = 32; off; off >>= 1) {
                posv += __shfl_xor(posv, off);
                boxv += __shfl_xor(boxv, off);
            }
        }
        if ((tid & 63) == 0) {
            if (nb) atomicAdd(&s_nn, (unsigned int)__popcll(nb));
            if (pb) {
                atomicAdd(&s_np, (unsigned int)__popcll(pb));
                atomicAdd(&s_ps, posv);
                atomicAdd(&s_bs, boxv);
            }
        }
        __syncthreads();
        unsigned int* sg = scal + b * 16;
        if (tid == 0) {
            if (s_nn) atomicAdd(&sg[1], s_nn);
            if (s_np) {
                atomicAdd(&sg[0], s_np);
                atomicAdd((float*)(sg + 2), s_ps);
                atomicAdd((float*)(sg + 3), s_bs);
            }
        }
        if (hc8[tid]) {
            atomicAdd(&l1c[b * 256 + tid], hc8[tid]);
            atomicAdd(&l1s[b * 256 + tid], hs8[tid]);
        }
        __syncthreads();
    }
    gbar(bar, 1, GRID);

    // ================= phase B: per-block sel1 recompute, then L2 hist (direct global atomics) =====
    if (tid < NB) {
        const unsigned int np = scal[tid * 16 + 0];
        const unsigned int nn = scal[tid * 16 + 1];
        unsigned int kk = 0;
        if (np > 0) { const unsigned int kp = np * 3u; kk = (kp < nn) ? kp : nn; }
        sh_k[tid] = kk; sh_np[tid] = np;
    }
    __syncthreads();
    for (int b = 0; b < NB; ++b) {
        if (sh_k[b] == 0u) continue;   // block-uniform
        unsigned int c, cab; float sab;
        sel256(l1c + b * 256, l1s + b * 256, sh_k[b], s_sc, s_ss, s_res, &s_resf, &c, &cab, &sab);
        if (tid == 0) { sh_c1[b] = c; sh_cab1[b] = cab; sh_sab1[b] = sab; }
        __syncthreads();
    }
    for (int t = bid; t < NT; t += GRID) {
        const int b = t / CPI;
        if (sh_k[b] == 0u) continue;
        const int i = (t - b * CPI) * 256 + tid;
        if (i < NA) {
            const unsigned int key = keys[(size_t)b * NA + i];
            if (key && (key >> 24) == sh_c1[b]) {
                const unsigned int bin = (key >> 12) & 0xfffu;
                atomicAdd(&l2c[b * 4096 + bin], 1u);
                atomicAdd(&l2s[b * 4096 + bin], key2f(key));
            }
        }
    }
    gbar(bar, 2, GRID);

    // ================= phase C: per-block sel2 recompute, then L3 hist =====
    for (int b = 0; b < NB; ++b) {
        if (sh_k[b] == 0u) continue;
        const unsigned int t2 = sh_k[b] - sh_cab1[b];
        unsigned int c, cab; float sab;
        sel4096g(l2c + b * 4096, l2s + b * 4096, t2, s_sc, s_ss, s_res, &s_resf, &c, &cab, &sab);
        if (tid == 0) { sh_c2[b] = c; sh_t2[b] = t2; sh_cab2[b] = cab; sh_sab2[b] = sab; }
        __syncthreads();
    }
    for (int t = bid; t < NT; t += GRID) {
        const int b = t / CPI;
        if (sh_k[b] == 0u) continue;
        const unsigned int top20 = (sh_c1[b] << 12) | sh_c2[b];
        const int i = (t - b * CPI) * 256 + tid;
        if (i < NA) {
            const unsigned int key = keys[(size_t)b * NA + i];
            if (key && (key >> 12) == top20) {
                const unsigned int bin = key & 0xfffu;
                atomicAdd(&l3c[b * 4096 + bin], 1u);
                atomicAdd(&l3s[b * 4096 + bin], key2f(key));
            }
        }
    }
    gbar(bar, 3, GRID);

    // ================= phase D: blocks 0..7 do sel3 + finalize =====
    if (bid < NB) {
        const int b = bid;
        float s_top = 0.0f;
        const unsigned int k = sh_k[b], np = sh_np[b];
        if (k > 0) {
            const unsigned int t3 = sh_t2[b] - sh_cab2[b];
            unsigned int c3, cab3; float sab3;
            sel4096g(l3c + b * 4096, l3s + b * 4096, t3, s_sc, s_ss, s_res, &s_resf, &c3, &cab3, &sab3);
            const unsigned int keyv = (sh_c1[b] << 24) | (sh_c2[b] << 12) | c3;
            const float v = key2f(keyv);
            const unsigned int rem = t3 - cab3;    // exact tie handling: leaf keys identical
            s_top = sh_sab1[b] + sh_sab2[b] + sab3 + (float)rem * v;
        }
        if (tid == 0) {
            float cls_loss = 0.0f, box_loss = 0.0f;
            if (np > 0) {
                const float* fsc = (const float*)(scal + b * 16);
                const float pos_mean = fsc[2] / (float)np;
                const float neg_mean = s_top / (float)((k > 0) ? k : 1u);
                cls_loss = pos_mean + neg_mean;
                box_loss = fsc[3] / (float)(4u * np);
            }
            out[b] = cls_loss;
            out[NB + b] = box_loss;
        }
    }
}

extern "C" void kernel_launch(void* const* d_in, const int* in_sizes, int n_in,
                              void* d_out, int out_size, void* d_ws, size_t ws_size,
                              hipStream_t stream) {
    const float* cls     = (const float*)d_in[0];   // (B, A, 2)
    const float* reg     = (const float*)d_in[1];   // (B, A, 4)
    const float* anchors = (const float*)d_in[2];   // (1, A, 4)
    const float* ann     = (const float*)d_in[3];   // (B, M, 4)
    (void)in_sizes; (void)n_in; (void)out_size; (void)ws_size;
    k_all<<<dim3(GRID), 256, 0, stream>>>(cls, reg, anchors, ann,
                                          (unsigned int*)d_ws, (float*)d_out);
}

// Round 4
// 283.881 us; speedup vs baseline: 1.9642x; 1.9642x over previous
//
#include <hip/hip_runtime.h>
#include <stdint.h>

#define NA 200000
#define NB 8
#define NM 64
#define CPI 782                 // anchor chunks of 256 per image (782*256 = 200192)
#define BPI 64                  // blocks per image in tail kernels
#define GRID2 (NB*BPI)          // 512

// ---- workspace layout (dword offsets) ----
// scal: 8 images x 16 slots: [0]np [1]nn [2]ps(f32) [3]bs(f32)
#define O_SCAL 0
#define O_L1C  128                   // 8 x 256
#define O_L1S  (O_L1C+2048)
#define O_L2C  (O_L1S+2048)          // 8 x 4096 (16-B aligned: byte 16896)
#define O_L2S  (O_L2C+32768)
#define O_L3C  (O_L2S+32768)
#define O_L3S  (O_L3C+32768)
#define O_KEYS (O_L3S+32768)         // 8 x 200000
#define N_ZERO O_KEYS                // 135296 dwords ~ 529 KB

__device__ __forceinline__ unsigned int f2key(float f) {
    unsigned int u = __float_as_uint(f);
    return (u & 0x80000000u) ? ~u : (u | 0x80000000u);
}
__device__ __forceinline__ float key2f(unsigned int k) {
    return (k & 0x80000000u) ? __uint_as_float(k & 0x7fffffffu) : __uint_as_float(~k);
}

// exact select over a 256-bin (cnt,sum) histogram. Block-collective.
// out: crossing bin c, cab = count strictly above c, sab = sum strictly above c.
__device__ void sel256(const unsigned int* cnt, const float* sum, unsigned int target,
                       unsigned int* s_sc, float* s_ss, unsigned int* s_res, float* s_resf,
                       unsigned int* c, unsigned int* cab, float* sab) {
    const int t = threadIdx.x;
    s_sc[t] = cnt[t]; s_ss[t] = sum[t];
    __syncthreads();
    for (int d = 1; d < 256; d <<= 1) {      // inclusive suffix scan
        unsigned int uc = (t + d < 256) ? s_sc[t + d] : 0u;
        float fs = (t + d < 256) ? s_ss[t + d] : 0.0f;
        __syncthreads();
        s_sc[t] += uc; s_ss[t] += fs;
        __syncthreads();
    }
    unsigned int nxt = (t < 255) ? s_sc[t + 1] : 0u;
    float nxs = (t < 255) ? s_ss[t + 1] : 0.0f;
    if (s_sc[t] >= target && nxt < target) { s_res[0] = (unsigned int)t; s_res[1] = nxt; *s_resf = nxs; }
    __syncthreads();
    *c = s_res[0]; *cab = s_res[1]; *sab = *s_resf;
    __syncthreads();
}

// exact select over a 4096-bin global (cnt,sum) histogram. Block-collective.
__device__ void sel4096g(const unsigned int* cnt, const float* sum, unsigned int target,
                         unsigned int* s_sc, float* s_ss, unsigned int* s_res, float* s_resf,
                         unsigned int* c, unsigned int* cab, float* sab) {
    const int t = threadIdx.x;
    unsigned int cb[16]; float sb[16];
    const uint4*  cp = (const uint4*)(cnt + t * 16);
    const float4* sp = (const float4*)(sum + t * 16);
#pragma unroll
    for (int j = 0; j < 4; ++j) {
        uint4 u = cp[j];  cb[4*j] = u.x; cb[4*j+1] = u.y; cb[4*j+2] = u.z; cb[4*j+3] = u.w;
        float4 f = sp[j]; sb[4*j] = f.x; sb[4*j+1] = f.y; sb[4*j+2] = f.z; sb[4*j+3] = f.w;
    }
    unsigned int cc = 0; float cs = 0.0f;
#pragma unroll
    for (int j = 0; j < 16; ++j) { cc += cb[j]; cs += sb[j]; }
    s_sc[t] = cc; s_ss[t] = cs;
    __syncthreads();
    for (int d = 1; d < 256; d <<= 1) {
        unsigned int uc = (t + d < 256) ? s_sc[t + d] : 0u;
        float fs = (t + d < 256) ? s_ss[t + d] : 0.0f;
        __syncthreads();
        s_sc[t] += uc; s_ss[t] += fs;
        __syncthreads();
    }
    unsigned int run = (t < 255) ? s_sc[t + 1] : 0u;
    float runs = (t < 255) ? s_ss[t + 1] : 0.0f;
#pragma unroll
    for (int j = 15; j >= 0; --j) {
        const unsigned int prev = run; const float prevs = runs;
        run += cb[j]; runs += sb[j];
        if (run >= target && prev < target) {
            s_res[0] = (unsigned int)(t * 16 + j); s_res[1] = prev; *s_resf = prevs;
        }
    }
    __syncthreads();
    *c = s_res[0]; *cab = s_res[1]; *sab = *s_resf;
    __syncthreads();
}

// ---------------- K1: IoU argmax (cross-multiply, no divide), stats, keys, L1 hist ----------------
__global__ __launch_bounds__(256, 4) void k_main(
    const float* __restrict__ cls, const float* __restrict__ reg,
    const float* __restrict__ anchors, const float* __restrict__ ann,
    unsigned int* __restrict__ scal, unsigned int* __restrict__ l1cnt,
    float* __restrict__ l1sum, unsigned int* __restrict__ keys)
{
    __shared__ float4 sbox[NM];
    __shared__ float  areab[NM];
    __shared__ unsigned int hc8[256];
    __shared__ float hs8[256];
    __shared__ unsigned int s_np, s_nn;
    __shared__ float s_ps, s_bs;

    const int b = blockIdx.y;
    const int tid = threadIdx.x;
    if (tid < NM) {
        float4 bb = ((const float4*)ann)[b * NM + tid];
        if (!(bb.x > 0.0f)) {   // invalid -> inter 0, ua inf, ratio 0 (verified bit-exact vs ref)
            bb.x = __builtin_inff(); bb.y = __builtin_inff();
            bb.z = -__builtin_inff(); bb.w = -__builtin_inff();
        }
        sbox[tid] = bb;
        areab[tid] = (bb.z - bb.x) * (bb.w - bb.y);
    }
    hc8[tid] = 0u; hs8[tid] = 0.0f;
    if (tid == 0) { s_np = 0u; s_nn = 0u; s_ps = 0.0f; s_bs = 0.0f; }
    __syncthreads();

    const int i = blockIdx.x * 256 + tid;
    bool pos = false, neg = false;
    float posv = 0.0f, boxv = 0.0f;
    if (i < NA) {
        const float4 a4 = ((const float4*)anchors)[i];
        float bi = -1.0f, bu = 1.0f;    // best ratio held as (inter, ua) pair
        int arg = 0;
        {
#pragma clang fp contract(off)
            const float area_a = (a4.z - a4.x) * (a4.w - a4.y);
#pragma unroll 8
            for (int m = 0; m < NM; ++m) {
                const float4 bb = sbox[m];
                const float ab = areab[m];
                const float iw = fmaxf(fminf(a4.z, bb.z) - fmaxf(a4.x, bb.x), 0.0f);
                const float ih = fmaxf(fminf(a4.w, bb.w) - fmaxf(a4.y, bb.y), 0.0f);
                const float inter = iw * ih;
                const float ua = fmaxf(area_a + ab - inter, 1e-8f);
                if (inter * bu > bi * ua) { bi = inter; bu = ua; arg = m; }
            }
            pos = (bi >= 0.5f * bu);
            neg = (bi <  0.3f * bu);
        }
        const float2 cv = ((const float2*)cls)[(size_t)b * NA + i];
        unsigned int key = 0u;   // excluded anchors: key 0 (< any real key >= 0x00800000)
        if (neg) {
            const float nl = -cv.y;
            key = f2key(nl);
            atomicAdd(&hc8[key >> 24], 1u);
            atomicAdd(&hs8[key >> 24], nl);
        }
        keys[(size_t)b * NA + i] = key;
        if (pos) {
            posv = -cv.x;
            const float4 g = sbox[arg];
            const float aw = a4.z - a4.x, ah = a4.w - a4.y;
            const float acx = a4.x + 0.5f * aw, acy = a4.y + 0.5f * ah;
            const float gw = g.z - g.x, gh = g.w - g.y;
            const float gcx = g.x + 0.5f * gw, gcy = g.y + 0.5f * gh;
            const float t0 = ((gcx - acx) / (aw + 1e-14f)) / 0.1f;
            const float t1 = ((gcy - acy) / (ah + 1e-14f)) / 0.1f;
            const float t2 = logf(gw / aw) / 0.2f;
            const float t3 = logf(gh / ah) / 0.2f;
            const float4 r = ((const float4*)reg)[(size_t)b * NA + i];
            const float d0 = fabsf(t0 - r.x);
            const float d1 = fabsf(t1 - r.y);
            const float d2 = fabsf(t2 - r.z);
            const float d3 = fabsf(t3 - r.w);
            const float l0 = (d0 < 1.0f) ? 0.5f * d0 * d0 : d0 - 0.5f;
            const float l1 = (d1 < 1.0f) ? 0.5f * d1 * d1 : d1 - 0.5f;
            const float l2 = (d2 < 1.0f) ? 0.5f * d2 * d2 : d2 - 0.5f;
            const float l3 = (d3 < 1.0f) ? 0.5f * d3 * d3 : d3 - 0.5f;
            boxv = l0 + l1 + l2 + l3;
        }
    }

    // wave -> block -> one global flush per block
    const unsigned long long pb = __ballot(pos);
    const unsigned long long nb = __ballot(neg);
    if (pb) {
        for (int off = 32; off; off >>= 1) {
            posv += __shfl_xor(posv, off);
            boxv += __shfl_xor(boxv, off);
        }
    }
    if ((tid & 63) == 0) {
        if (nb) atomicAdd(&s_nn, (unsigned int)__popcll(nb));
        if (pb) {
            atomicAdd(&s_np, (unsigned int)__popcll(pb));
            atomicAdd(&s_ps, posv);
            atomicAdd(&s_bs, boxv);
        }
    }
    __syncthreads();
    unsigned int* sg = scal + b * 16;
    if (tid == 0) {
        if (s_nn) atomicAdd(&sg[1], s_nn);
        if (s_np) {
            atomicAdd(&sg[0], s_np);
            atomicAdd((float*)(sg + 2), s_ps);
            atomicAdd((float*)(sg + 3), s_bs);
        }
    }
    if (hc8[tid]) {
        atomicAdd(&l1cnt[b * 256 + tid], hc8[tid]);
        atomicAdd(&l1sum[b * 256 + tid], hs8[tid]);
    }
}

// ---------------- K2: per-block sel1 recompute + L2 hist (512 blocks, 64/image) ----------------
__global__ __launch_bounds__(256) void k_hist2(
    const unsigned int* __restrict__ keys, const unsigned int* __restrict__ scal,
    const unsigned int* __restrict__ l1c, const float* __restrict__ l1s,
    unsigned int* __restrict__ l2c, float* __restrict__ l2s)
{
    __shared__ unsigned int s_sc[256];
    __shared__ float s_ss[256];
    __shared__ unsigned int s_res[2];
    __shared__ float s_resf;
    const int b = blockIdx.x >> 6;
    const int sub = blockIdx.x & 63;
    const int tid = threadIdx.x;
    const unsigned int np = scal[b * 16], nn = scal[b * 16 + 1];
    unsigned int k = 0;
    if (np) { const unsigned int kp = np * 3u; k = (kp < nn) ? kp : nn; }
    if (k == 0) return;   // block-uniform
    unsigned int c1, cab1; float sab1;
    sel256(l1c + b * 256, l1s + b * 256, k, s_sc, s_ss, s_res, &s_resf, &c1, &cab1, &sab1);
    for (int c = sub; c < CPI; c += BPI) {
        const int i = c * 256 + tid;
        if (i < NA) {
            const unsigned int key = keys[(size_t)b * NA + i];
            if (key && (key >> 24) == c1) {
                const unsigned int bin = (key >> 12) & 0xfffu;
                atomicAdd(&l2c[b * 4096 + bin], 1u);
                atomicAdd(&l2s[b * 4096 + bin], key2f(key));
            }
        }
    }
}

// ---------------- K3: per-block sel1+sel2 recompute + L3 hist ----------------
__global__ __launch_bounds__(256) void k_hist3(
    const unsigned int* __restrict__ keys, const unsigned int* __restrict__ scal,
    const unsigned int* __restrict__ l1c, const float* __restrict__ l1s,
    const unsigned int* __restrict__ l2c, const float* __restrict__ l2s,
    unsigned int* __restrict__ l3c, float* __restrict__ l3s)
{
    __shared__ unsigned int s_sc[256];
    __shared__ float s_ss[256];
    __shared__ unsigned int s_res[2];
    __shared__ float s_resf;
    const int b = blockIdx.x >> 6;
    const int sub = blockIdx.x & 63;
    const int tid = threadIdx.x;
    const unsigned int np = scal[b * 16], nn = scal[b * 16 + 1];
    unsigned int k = 0;
    if (np) { const unsigned int kp = np * 3u; k = (kp < nn) ? kp : nn; }
    if (k == 0) return;
    unsigned int c1, cab1; float sab1;
    sel256(l1c + b * 256, l1s + b * 256, k, s_sc, s_ss, s_res, &s_resf, &c1, &cab1, &sab1);
    unsigned int c2, cab2; float sab2;
    sel4096g(l2c + b * 4096, l2s + b * 4096, k - cab1, s_sc, s_ss, s_res, &s_resf, &c2, &cab2, &sab2);
    const unsigned int top20 = (c1 << 12) | c2;
    for (int c = sub; c < CPI; c += BPI) {
        const int i = c * 256 + tid;
        if (i < NA) {
            const unsigned int key = keys[(size_t)b * NA + i];
            if (key && (key >> 12) == top20) {
                const unsigned int bin = key & 0xfffu;
                atomicAdd(&l3c[b * 4096 + bin], 1u);
                atomicAdd(&l3s[b * 4096 + bin], key2f(key));
            }
        }
    }
}

// ---------------- K4: full select chain recompute + finalize (8 blocks) ----------------
__global__ __launch_bounds__(256) void k_final(
    const unsigned int* __restrict__ scal,
    const unsigned int* __restrict__ l1c, const float* __restrict__ l1s,
    const unsigned int* __restrict__ l2c, const float* __restrict__ l2s,
    const unsigned int* __restrict__ l3c, const float* __restrict__ l3s,
    float* __restrict__ out)
{
    __shared__ unsigned int s_sc[256];
    __shared__ float s_ss[256];
    __shared__ unsigned int s_res[2];
    __shared__ float s_resf;
    const int b = blockIdx.x;
    const unsigned int np = scal[b * 16], nn = scal[b * 16 + 1];
    unsigned int k = 0;
    if (np) { const unsigned int kp = np * 3u; k = (kp < nn) ? kp : nn; }
    float s_top = 0.0f;
    if (k > 0) {   // block-uniform
        unsigned int c1, cab1; float sab1;
        sel256(l1c + b * 256, l1s + b * 256, k, s_sc, s_ss, s_res, &s_resf, &c1, &cab1, &sab1);
        const unsigned int t2 = k - cab1;
        unsigned int c2, cab2; float sab2;
        sel4096g(l2c + b * 4096, l2s + b * 4096, t2, s_sc, s_ss, s_res, &s_resf, &c2, &cab2, &sab2);
        const unsigned int t3 = t2 - cab2;
        unsigned int c3, cab3; float sab3;
        sel4096g(l3c + b * 4096, l3s + b * 4096, t3, s_sc, s_ss, s_res, &s_resf, &c3, &cab3, &sab3);
        const unsigned int keyv = (c1 << 24) | (c2 << 12) | c3;
        const float v = key2f(keyv);
        const unsigned int rem = t3 - cab3;      // exact tie handling: leaf keys identical
        s_top = sab1 + sab2 + sab3 + (float)rem * v;
    }
    if (threadIdx.x == 0) {
        float cls_loss = 0.0f, box_loss = 0.0f;
        if (np > 0) {
            const float* fsc = (const float*)(scal + b * 16);
            const float pos_mean = fsc[2] / (float)np;
            const float neg_mean = s_top / (float)((k > 0) ? k : 1u);
            cls_loss = pos_mean + neg_mean;
            box_loss = fsc[3] / (float)(4u * np);
        }
        out[b] = cls_loss;
        out[NB + b] = box_loss;
    }
}

extern "C" void kernel_launch(void* const* d_in, const int* in_sizes, int n_in,
                              void* d_out, int out_size, void* d_ws, size_t ws_size,
                              hipStream_t stream) {
    const float* cls     = (const float*)d_in[0];   // (B, A, 2)
    const float* reg     = (const float*)d_in[1];   // (B, A, 4)
    const float* anchors = (const float*)d_in[2];   // (1, A, 4)
    const float* ann     = (const float*)d_in[3];   // (B, M, 4)
    unsigned int* ws = (unsigned int*)d_ws;
    unsigned int* scal = ws + O_SCAL;
    unsigned int* l1c  = ws + O_L1C;   float* l1s = (float*)(ws + O_L1S);
    unsigned int* l2c  = ws + O_L2C;   float* l2s = (float*)(ws + O_L2S);
    unsigned int* l3c  = ws + O_L3C;   float* l3s = (float*)(ws + O_L3S);
    unsigned int* keys = ws + O_KEYS;
    (void)in_sizes; (void)n_in; (void)out_size; (void)ws_size;

    hipMemsetAsync(d_ws, 0, (size_t)N_ZERO * 4, stream);
    k_main <<<dim3(CPI, NB), 256, 0, stream>>>(cls, reg, anchors, ann, scal, l1c, l1s, keys);
    k_hist2<<<dim3(GRID2),   256, 0, stream>>>(keys, scal, l1c, l1s, l2c, l2s);
    k_hist3<<<dim3(GRID2),   256, 0, stream>>>(keys, scal, l1c, l1s, l2c, l2s, l3c, l3s);
    k_final<<<dim3(NB),      256, 0, stream>>>(scal, l1c, l1s, l2c, l2s, l3c, l3s, (float*)d_out);
}

// Round 5
// 276.205 us; speedup vs baseline: 2.0188x; 1.0278x over previous
//
#include <hip/hip_runtime.h>
#include <stdint.h>

#define NA 200000
#define NB 8
#define NM 64
#define APB 512                 // anchors per k_main block (2 per thread)
#define CPB 391                 // 391*512 = 200192 >= 200000

// ---- workspace layout (dword offsets) ----
// scal: 8 images x 16 slots: [0]np [1]nn [2]ps(f32) [3]bs(f32)
#define O_SCAL 0
#define O_L1C  128                   // 8 x 256 counts
#define O_L1S  2176                  // 8 x 256 sums
#define O_KEYS 4224                  // 8 x 200000 keys
#define N_ZERO 4224                  // zero scal + L1 hist only (16.9 KB)

__device__ __forceinline__ unsigned int f2key(float f) {
    unsigned int u = __float_as_uint(f);
    return (u & 0x80000000u) ? ~u : (u | 0x80000000u);
}
__device__ __forceinline__ float key2f(unsigned int k) {
    return (k & 0x80000000u) ? __uint_as_float(k & 0x7fffffffu) : __uint_as_float(~k);
}

// per-anchor epilogue: key write + LDS L1 hist + pos-path box loss accumulation
__device__ __forceinline__ void epi(
    int b, int i, float4 a4, int arg, bool pos, bool neg,
    const float* __restrict__ cls, const float* __restrict__ reg,
    const float4* sbox, unsigned int* __restrict__ keys,
    unsigned int* hc8, float* hs8, float& posv, float& boxv)
{
    const float2 cv = ((const float2*)cls)[(size_t)b * NA + i];
    unsigned int key = 0u;   // excluded anchors: key 0 (< any real key >= 0x00800000)
    if (neg) {
        const float nl = -cv.y;
        key = f2key(nl);
        atomicAdd(&hc8[key >> 24], 1u);
        atomicAdd(&hs8[key >> 24], nl);
    }
    keys[(size_t)b * NA + i] = key;
    if (pos) {
        posv += -cv.x;
        const float4 g = sbox[arg];
        const float aw = a4.z - a4.x, ah = a4.w - a4.y;
        const float acx = a4.x + 0.5f * aw, acy = a4.y + 0.5f * ah;
        const float gw = g.z - g.x, gh = g.w - g.y;
        const float gcx = g.x + 0.5f * gw, gcy = g.y + 0.5f * gh;
        const float t0 = ((gcx - acx) / (aw + 1e-14f)) / 0.1f;
        const float t1 = ((gcy - acy) / (ah + 1e-14f)) / 0.1f;
        const float t2 = logf(gw / aw) / 0.2f;
        const float t3 = logf(gh / ah) / 0.2f;
        const float4 r = ((const float4*)reg)[(size_t)b * NA + i];
        const float d0 = fabsf(t0 - r.x);
        const float d1 = fabsf(t1 - r.y);
        const float d2 = fabsf(t2 - r.z);
        const float d3 = fabsf(t3 - r.w);
        const float l0 = (d0 < 1.0f) ? 0.5f * d0 * d0 : d0 - 0.5f;
        const float l1 = (d1 < 1.0f) ? 0.5f * d1 * d1 : d1 - 0.5f;
        const float l2 = (d2 < 1.0f) ? 0.5f * d2 * d2 : d2 - 0.5f;
        const float l3 = (d3 < 1.0f) ? 0.5f * d3 * d3 : d3 - 0.5f;
        boxv += l0 + l1 + l2 + l3;
    }
}

// ---------------- K1: IoU argmax (cross-multiply), 2 anchors/thread, 8-box register blocks ----
__global__ __launch_bounds__(256, 4) void k_main(
    const float* __restrict__ cls, const float* __restrict__ reg,
    const float* __restrict__ anchors, const float* __restrict__ ann,
    unsigned int* __restrict__ scal, unsigned int* __restrict__ l1cnt,
    float* __restrict__ l1sum, unsigned int* __restrict__ keys)
{
    __shared__ float4 sbox[NM];
    __shared__ unsigned int hc8[256];
    __shared__ float hs8[256];
    __shared__ unsigned int s_np, s_nn;
    __shared__ float s_ps, s_bs;

    const int b = blockIdx.y;
    const int tid = threadIdx.x;
    if (tid < NM) {
        float4 bb = ((const float4*)ann)[b * NM + tid];
        if (!(bb.x > 0.0f)) {   // invalid -> inter 0, ua inf, ratio 0 (bit-exact vs ref, r3/r4)
            bb.x = __builtin_inff(); bb.y = __builtin_inff();
            bb.z = -__builtin_inff(); bb.w = -__builtin_inff();
        }
        sbox[tid] = bb;
    }
    hc8[tid] = 0u; hs8[tid] = 0.0f;
    if (tid == 0) { s_np = 0u; s_nn = 0u; s_ps = 0.0f; s_bs = 0.0f; }
    __syncthreads();

    const int i0 = blockIdx.x * APB + tid;
    const int i1 = i0 + 256;
    float4 A0 = make_float4(0.f, 0.f, 0.f, 0.f);
    float4 A1 = make_float4(0.f, 0.f, 0.f, 0.f);
    if (i0 < NA) A0 = ((const float4*)anchors)[i0];
    if (i1 < NA) A1 = ((const float4*)anchors)[i1];

    float bi0 = -1.0f, bu0 = 1.0f, bi1 = -1.0f, bu1 = 1.0f;
    int arg0 = 0, arg1 = 0;
    bool pos0, neg0, pos1, neg1;
    {
#pragma clang fp contract(off)
        const float aa0 = (A0.z - A0.x) * (A0.w - A0.y);
        const float aa1 = (A1.z - A1.x) * (A1.w - A1.y);
#pragma unroll 1
        for (int mo = 0; mo < NM; mo += 8) {
            float4 bb[8]; float ab[8];
#pragma unroll
            for (int j = 0; j < 8; ++j) {
                bb[j] = sbox[mo + j];                              // ds_read_b128, held in regs
                ab[j] = (bb[j].z - bb[j].x) * (bb[j].w - bb[j].y); // area in-register
            }
#pragma unroll
            for (int j = 0; j < 8; ++j) {
                {
                    const float iw = fmaxf(fminf(A0.z, bb[j].z) - fmaxf(A0.x, bb[j].x), 0.0f);
                    const float ih = fmaxf(fminf(A0.w, bb[j].w) - fmaxf(A0.y, bb[j].y), 0.0f);
                    const float inter = iw * ih;
                    const float ua = fmaxf(aa0 + ab[j] - inter, 1e-8f);
                    if (inter * bu0 > bi0 * ua) { bi0 = inter; bu0 = ua; arg0 = mo + j; }
                }
                {
                    const float iw = fmaxf(fminf(A1.z, bb[j].z) - fmaxf(A1.x, bb[j].x), 0.0f);
                    const float ih = fmaxf(fminf(A1.w, bb[j].w) - fmaxf(A1.y, bb[j].y), 0.0f);
                    const float inter = iw * ih;
                    const float ua = fmaxf(aa1 + ab[j] - inter, 1e-8f);
                    if (inter * bu1 > bi1 * ua) { bi1 = inter; bu1 = ua; arg1 = mo + j; }
                }
            }
        }
        pos0 = (bi0 >= 0.5f * bu0); neg0 = (bi0 < 0.3f * bu0);
        pos1 = (bi1 >= 0.5f * bu1); neg1 = (bi1 < 0.3f * bu1);
    }

    float posv = 0.0f, boxv = 0.0f;
    if (i0 < NA) epi(b, i0, A0, arg0, pos0, neg0, cls, reg, (const float4*)sbox, keys, hc8, hs8, posv, boxv);
    else { pos0 = false; neg0 = false; }
    if (i1 < NA) epi(b, i1, A1, arg1, pos1, neg1, cls, reg, (const float4*)sbox, keys, hc8, hs8, posv, boxv);
    else { pos1 = false; neg1 = false; }

    const unsigned long long pb0 = __ballot(pos0);
    const unsigned long long pb1 = __ballot(pos1);
    const unsigned long long nb0 = __ballot(neg0);
    const unsigned long long nb1 = __ballot(neg1);
    if (pb0 | pb1) {
        for (int off = 32; off; off >>= 1) {
            posv += __shfl_xor(posv, off);
            boxv += __shfl_xor(boxv, off);
        }
    }
    if ((tid & 63) == 0) {
        const unsigned int nc = (unsigned int)(__popcll(nb0) + __popcll(nb1));
        const unsigned int pc = (unsigned int)(__popcll(pb0) + __popcll(pb1));
        if (nc) atomicAdd(&s_nn, nc);
        if (pc) { atomicAdd(&s_np, pc); atomicAdd(&s_ps, posv); atomicAdd(&s_bs, boxv); }
    }
    __syncthreads();
    unsigned int* sg = scal + b * 16;
    if (tid == 0) {
        if (s_nn) atomicAdd(&sg[1], s_nn);
        if (s_np) {
            atomicAdd(&sg[0], s_np);
            atomicAdd((float*)(sg + 2), s_ps);
            atomicAdd((float*)(sg + 3), s_bs);
        }
    }
    if (hc8[tid]) {
        atomicAdd(&l1cnt[b * 256 + tid], hc8[tid]);
        atomicAdd(&l1sum[b * 256 + tid], hs8[tid]);
    }
}

// select over 4096-bin LDS histogram; 1024-thread block, threads <256 active.
// out: crossing bin c, cab = count strictly above, sab = sum strictly above.
__device__ void sel4096_lds(const unsigned int* hc, const float* hs, unsigned int target,
                            unsigned int* s_sc, float* s_ss, unsigned int* s_res, float* s_resf,
                            unsigned int* c, unsigned int* cab, float* sab)
{
    const int t = threadIdx.x;
    unsigned int cb[16]; float sb[16];
    if (t < 256) {
        unsigned int cc = 0; float cs = 0.0f;
#pragma unroll
        for (int j = 0; j < 16; ++j) {
            cb[j] = hc[t * 16 + j]; sb[j] = hs[t * 16 + j];
            cc += cb[j]; cs += sb[j];
        }
        s_sc[t] = cc; s_ss[t] = cs;
    }
    __syncthreads();
    for (int d = 1; d < 256; d <<= 1) {      // inclusive suffix scan over 256 partials
        unsigned int uc = 0; float fs = 0.0f;
        if (t < 256) { uc = (t + d < 256) ? s_sc[t + d] : 0u; fs = (t + d < 256) ? s_ss[t + d] : 0.0f; }
        __syncthreads();
        if (t < 256) { s_sc[t] += uc; s_ss[t] += fs; }
        __syncthreads();
    }
    if (t < 256) {
        unsigned int run = (t < 255) ? s_sc[t + 1] : 0u;
        float runs = (t < 255) ? s_ss[t + 1] : 0.0f;
#pragma unroll
        for (int j = 15; j >= 0; --j) {
            const unsigned int prev = run; const float prevs = runs;
            run += cb[j]; runs += sb[j];
            if (run >= target && prev < target) {
                s_res[0] = (unsigned int)(t * 16 + j); s_res[1] = prev; *s_resf = prevs;
            }
        }
    }
    __syncthreads();
    *c = s_res[0]; *cab = s_res[1]; *sab = *s_resf;
    __syncthreads();
}

// ---------------- K2: fused select chain + finalize. 1 block/image, 1024 threads ----------------
__global__ __launch_bounds__(1024) void k_tail(
    const unsigned int* __restrict__ keys, const unsigned int* __restrict__ scal,
    const unsigned int* __restrict__ l1c, const float* __restrict__ l1s,
    float* __restrict__ out)
{
    __shared__ unsigned int hc[4096];
    __shared__ float hs[4096];
    __shared__ unsigned int s_sc[256];
    __shared__ float s_ss[256];
    __shared__ unsigned int s_res[2];
    __shared__ float s_resf;

    const int b = blockIdx.x;
    const int tid = threadIdx.x;
    const unsigned int np = scal[b * 16], nn = scal[b * 16 + 1];
    unsigned int k = 0;
    if (np) { const unsigned int kp = np * 3u; k = (kp < nn) ? kp : nn; }
    float s_top = 0.0f;

    if (k > 0) {   // block-uniform (scalar loads)
        // --- level 1: select over global 256-bin hist ---
        if (tid < 256) { s_sc[tid] = l1c[b * 256 + tid]; s_ss[tid] = l1s[b * 256 + tid]; }
        __syncthreads();
        for (int d = 1; d < 256; d <<= 1) {
            unsigned int uc = 0; float fs = 0.0f;
            if (tid < 256) { uc = (tid + d < 256) ? s_sc[tid + d] : 0u; fs = (tid + d < 256) ? s_ss[tid + d] : 0.0f; }
            __syncthreads();
            if (tid < 256) { s_sc[tid] += uc; s_ss[tid] += fs; }
            __syncthreads();
        }
        if (tid < 256) {
            const unsigned int nxt = (tid < 255) ? s_sc[tid + 1] : 0u;
            const float nxs = (tid < 255) ? s_ss[tid + 1] : 0.0f;
            if (s_sc[tid] >= k && nxt < k) { s_res[0] = (unsigned int)tid; s_res[1] = nxt; s_resf = nxs; }
        }
        __syncthreads();
        const unsigned int c1 = s_res[0];
        const unsigned int cab1 = s_res[1];
        const float sab1 = s_resf;
        const unsigned int t2 = k - cab1;
        __syncthreads();

        // --- level 2: 12-bit LDS hist of keys in bin c1 ---
        for (int j = tid; j < 4096; j += 1024) { hc[j] = 0u; hs[j] = 0.0f; }
        __syncthreads();
        for (int i = tid; i < NA; i += 1024) {
            const unsigned int key = keys[(size_t)b * NA + i];
            if (key && (key >> 24) == c1) {
                const unsigned int bin = (key >> 12) & 0xfffu;
                atomicAdd(&hc[bin], 1u);
                atomicAdd(&hs[bin], key2f(key));
            }
        }
        __syncthreads();
        unsigned int c2, cab2; float sab2;
        sel4096_lds(hc, hs, t2, s_sc, s_ss, s_res, &s_resf, &c2, &cab2, &sab2);
        const unsigned int t3 = t2 - cab2;
        const unsigned int top20 = (c1 << 12) | c2;

        // --- level 3: low-12-bit LDS hist of keys in (c1,c2) ---
        for (int j = tid; j < 4096; j += 1024) { hc[j] = 0u; hs[j] = 0.0f; }
        __syncthreads();
        for (int i = tid; i < NA; i += 1024) {
            const unsigned int key = keys[(size_t)b * NA + i];
            if (key && (key >> 12) == top20) {
                const unsigned int bin = key & 0xfffu;
                atomicAdd(&hc[bin], 1u);
                atomicAdd(&hs[bin], key2f(key));
            }
        }
        __syncthreads();
        unsigned int c3, cab3; float sab3;
        sel4096_lds(hc, hs, t3, s_sc, s_ss, s_res, &s_resf, &c3, &cab3, &sab3);

        const unsigned int keyv = (c1 << 24) | (c2 << 12) | c3;
        const float v = key2f(keyv);
        const unsigned int rem = t3 - cab3;      // exact tie handling: leaf keys identical
        s_top = sab1 + sab2 + sab3 + (float)rem * v;
    }

    if (tid == 0) {
        float cls_loss = 0.0f, box_loss = 0.0f;
        if (np > 0) {
            const float* fsc = (const float*)(scal + b * 16);
            const float pos_mean = fsc[2] / (float)np;
            const float neg_mean = s_top / (float)((k > 0) ? k : 1u);
            cls_loss = pos_mean + neg_mean;
            box_loss = fsc[3] / (float)(4u * np);
        }
        out[b] = cls_loss;
        out[NB + b] = box_loss;
    }
}

extern "C" void kernel_launch(void* const* d_in, const int* in_sizes, int n_in,
                              void* d_out, int out_size, void* d_ws, size_t ws_size,
                              hipStream_t stream) {
    const float* cls     = (const float*)d_in[0];   // (B, A, 2)
    const float* reg     = (const float*)d_in[1];   // (B, A, 4)
    const float* anchors = (const float*)d_in[2];   // (1, A, 4)
    const float* ann     = (const float*)d_in[3];   // (B, M, 4)
    unsigned int* ws = (unsigned int*)d_ws;
    unsigned int* scal = ws + O_SCAL;
    unsigned int* l1c  = ws + O_L1C;   float* l1s = (float*)(ws + O_L1S);
    unsigned int* keys = ws + O_KEYS;
    (void)in_sizes; (void)n_in; (void)out_size; (void)ws_size;

    hipMemsetAsync(d_ws, 0, (size_t)N_ZERO * 4, stream);
    k_main<<<dim3(CPB, NB), 256,  0, stream>>>(cls, reg, anchors, ann, scal, l1c, l1s, keys);
    k_tail<<<dim3(NB),      1024, 0, stream>>>(keys, scal, l1c, l1s, (float*)d_out);
}

// Round 6
// 260.826 us; speedup vs baseline: 2.1378x; 1.0590x over previous
//
#include <hip/hip_runtime.h>
#include <stdint.h>

#define NA 200000
#define NB 8
#define NM 64
#define APB 512                 // anchors per k_main block (2 per thread)
#define CPB 391                 // 391*512 = 200192 >= 200000
#define NA4 50000               // NA/4 uint4 per image

// ---- workspace layout (dword offsets) ----
// scal: 8 images x 16 slots: [0]np [1]nn [2]ps(f32) [3]bs(f32)
#define O_SCAL 0
#define O_L1C  128                   // 8 x 256 counts
#define O_L1S  2176                  // 8 x 256 sums
#define O_KEYS 4224                  // 8 x 200000 keys (byte offset 16896, 16B-aligned)
#define N_ZERO 4224                  // zero scal + L1 hist only (16.9 KB)

__device__ __forceinline__ unsigned int f2key(float f) {
    unsigned int u = __float_as_uint(f);
    return (u & 0x80000000u) ? ~u : (u | 0x80000000u);
}
__device__ __forceinline__ float key2f(unsigned int k) {
    return (k & 0x80000000u) ? __uint_as_float(k & 0x7fffffffu) : __uint_as_float(~k);
}

// per-anchor epilogue: key write + LDS L1 hist + pos-path box loss accumulation
__device__ __forceinline__ void epi(
    int b, int i, float4 a4, int arg, bool pos, bool neg,
    const float* __restrict__ cls, const float* __restrict__ reg,
    const float4* sbox, unsigned int* __restrict__ keys,
    unsigned int* hc8, float* hs8, float& posv, float& boxv)
{
    const float2 cv = ((const float2*)cls)[(size_t)b * NA + i];
    unsigned int key = 0u;   // excluded anchors: key 0 (< any real key >= 0x00800000)
    if (neg) {
        const float nl = -cv.y;
        key = f2key(nl);
        atomicAdd(&hc8[key >> 24], 1u);
        atomicAdd(&hs8[key >> 24], nl);
    }
    keys[(size_t)b * NA + i] = key;
    if (pos) {
        posv += -cv.x;
        const float4 g = sbox[arg];
        const float aw = a4.z - a4.x, ah = a4.w - a4.y;
        const float acx = a4.x + 0.5f * aw, acy = a4.y + 0.5f * ah;
        const float gw = g.z - g.x, gh = g.w - g.y;
        const float gcx = g.x + 0.5f * gw, gcy = g.y + 0.5f * gh;
        const float t0 = ((gcx - acx) / (aw + 1e-14f)) / 0.1f;
        const float t1 = ((gcy - acy) / (ah + 1e-14f)) / 0.1f;
        const float t2 = logf(gw / aw) / 0.2f;
        const float t3 = logf(gh / ah) / 0.2f;
        const float4 r = ((const float4*)reg)[(size_t)b * NA + i];
        const float d0 = fabsf(t0 - r.x);
        const float d1 = fabsf(t1 - r.y);
        const float d2 = fabsf(t2 - r.z);
        const float d3 = fabsf(t3 - r.w);
        const float l0 = (d0 < 1.0f) ? 0.5f * d0 * d0 : d0 - 0.5f;
        const float l1 = (d1 < 1.0f) ? 0.5f * d1 * d1 : d1 - 0.5f;
        const float l2 = (d2 < 1.0f) ? 0.5f * d2 * d2 : d2 - 0.5f;
        const float l3 = (d3 < 1.0f) ? 0.5f * d3 * d3 : d3 - 0.5f;
        boxv += l0 + l1 + l2 + l3;
    }
}

// ---------------- K1: IoU argmax (cross-multiply), 2 anchors/thread, 8-box register blocks ----
// UNCHANGED from round 5 (verified absmax 0.0) — do not touch the inner loop.
__global__ __launch_bounds__(256, 4) void k_main(
    const float* __restrict__ cls, const float* __restrict__ reg,
    const float* __restrict__ anchors, const float* __restrict__ ann,
    unsigned int* __restrict__ scal, unsigned int* __restrict__ l1cnt,
    float* __restrict__ l1sum, unsigned int* __restrict__ keys)
{
    __shared__ float4 sbox[NM];
    __shared__ unsigned int hc8[256];
    __shared__ float hs8[256];
    __shared__ unsigned int s_np, s_nn;
    __shared__ float s_ps, s_bs;

    const int b = blockIdx.y;
    const int tid = threadIdx.x;
    if (tid < NM) {
        float4 bb = ((const float4*)ann)[b * NM + tid];
        if (!(bb.x > 0.0f)) {   // invalid -> inter 0, ua inf, ratio 0 (bit-exact vs ref, r3/r4)
            bb.x = __builtin_inff(); bb.y = __builtin_inff();
            bb.z = -__builtin_inff(); bb.w = -__builtin_inff();
        }
        sbox[tid] = bb;
    }
    hc8[tid] = 0u; hs8[tid] = 0.0f;
    if (tid == 0) { s_np = 0u; s_nn = 0u; s_ps = 0.0f; s_bs = 0.0f; }
    __syncthreads();

    const int i0 = blockIdx.x * APB + tid;
    const int i1 = i0 + 256;
    float4 A0 = make_float4(0.f, 0.f, 0.f, 0.f);
    float4 A1 = make_float4(0.f, 0.f, 0.f, 0.f);
    if (i0 < NA) A0 = ((const float4*)anchors)[i0];
    if (i1 < NA) A1 = ((const float4*)anchors)[i1];

    float bi0 = -1.0f, bu0 = 1.0f, bi1 = -1.0f, bu1 = 1.0f;
    int arg0 = 0, arg1 = 0;
    bool pos0, neg0, pos1, neg1;
    {
#pragma clang fp contract(off)
        const float aa0 = (A0.z - A0.x) * (A0.w - A0.y);
        const float aa1 = (A1.z - A1.x) * (A1.w - A1.y);
#pragma unroll 1
        for (int mo = 0; mo < NM; mo += 8) {
            float4 bb[8]; float ab[8];
#pragma unroll
            for (int j = 0; j < 8; ++j) {
                bb[j] = sbox[mo + j];                              // ds_read_b128, held in regs
                ab[j] = (bb[j].z - bb[j].x) * (bb[j].w - bb[j].y); // area in-register
            }
#pragma unroll
            for (int j = 0; j < 8; ++j) {
                {
                    const float iw = fmaxf(fminf(A0.z, bb[j].z) - fmaxf(A0.x, bb[j].x), 0.0f);
                    const float ih = fmaxf(fminf(A0.w, bb[j].w) - fmaxf(A0.y, bb[j].y), 0.0f);
                    const float inter = iw * ih;
                    const float ua = fmaxf(aa0 + ab[j] - inter, 1e-8f);
                    if (inter * bu0 > bi0 * ua) { bi0 = inter; bu0 = ua; arg0 = mo + j; }
                }
                {
                    const float iw = fmaxf(fminf(A1.z, bb[j].z) - fmaxf(A1.x, bb[j].x), 0.0f);
                    const float ih = fmaxf(fminf(A1.w, bb[j].w) - fmaxf(A1.y, bb[j].y), 0.0f);
                    const float inter = iw * ih;
                    const float ua = fmaxf(aa1 + ab[j] - inter, 1e-8f);
                    if (inter * bu1 > bi1 * ua) { bi1 = inter; bu1 = ua; arg1 = mo + j; }
                }
            }
        }
        pos0 = (bi0 >= 0.5f * bu0); neg0 = (bi0 < 0.3f * bu0);
        pos1 = (bi1 >= 0.5f * bu1); neg1 = (bi1 < 0.3f * bu1);
    }

    float posv = 0.0f, boxv = 0.0f;
    if (i0 < NA) epi(b, i0, A0, arg0, pos0, neg0, cls, reg, (const float4*)sbox, keys, hc8, hs8, posv, boxv);
    else { pos0 = false; neg0 = false; }
    if (i1 < NA) epi(b, i1, A1, arg1, pos1, neg1, cls, reg, (const float4*)sbox, keys, hc8, hs8, posv, boxv);
    else { pos1 = false; neg1 = false; }

    const unsigned long long pb0 = __ballot(pos0);
    const unsigned long long pb1 = __ballot(pos1);
    const unsigned long long nb0 = __ballot(neg0);
    const unsigned long long nb1 = __ballot(neg1);
    if (pb0 | pb1) {
        for (int off = 32; off; off >>= 1) {
            posv += __shfl_xor(posv, off);
            boxv += __shfl_xor(boxv, off);
        }
    }
    if ((tid & 63) == 0) {
        const unsigned int nc = (unsigned int)(__popcll(nb0) + __popcll(nb1));
        const unsigned int pc = (unsigned int)(__popcll(pb0) + __popcll(pb1));
        if (nc) atomicAdd(&s_nn, nc);
        if (pc) { atomicAdd(&s_np, pc); atomicAdd(&s_ps, posv); atomicAdd(&s_bs, boxv); }
    }
    __syncthreads();
    unsigned int* sg = scal + b * 16;
    if (tid == 0) {
        if (s_nn) atomicAdd(&sg[1], s_nn);
        if (s_np) {
            atomicAdd(&sg[0], s_np);
            atomicAdd((float*)(sg + 2), s_ps);
            atomicAdd((float*)(sg + 3), s_bs);
        }
    }
    if (hc8[tid]) {
        atomicAdd(&l1cnt[b * 256 + tid], hc8[tid]);
        atomicAdd(&l1sum[b * 256 + tid], hs8[tid]);
    }
}

// select over 4096-bin LDS histogram; 1024-thread block, threads <256 active.
__device__ void sel4096_lds(const unsigned int* hc, const float* hs, unsigned int target,
                            unsigned int* s_sc, float* s_ss, unsigned int* s_res, float* s_resf,
                            unsigned int* c, unsigned int* cab, float* sab)
{
    const int t = threadIdx.x;
    unsigned int cb[16]; float sb[16];
    if (t < 256) {
        unsigned int cc = 0; float cs = 0.0f;
#pragma unroll
        for (int j = 0; j < 16; ++j) {
            cb[j] = hc[t * 16 + j]; sb[j] = hs[t * 16 + j];
            cc += cb[j]; cs += sb[j];
        }
        s_sc[t] = cc; s_ss[t] = cs;
    }
    __syncthreads();
    for (int d = 1; d < 256; d <<= 1) {      // inclusive suffix scan over 256 partials
        unsigned int uc = 0; float fs = 0.0f;
        if (t < 256) { uc = (t + d < 256) ? s_sc[t + d] : 0u; fs = (t + d < 256) ? s_ss[t + d] : 0.0f; }
        __syncthreads();
        if (t < 256) { s_sc[t] += uc; s_ss[t] += fs; }
        __syncthreads();
    }
    if (t < 256) {
        unsigned int run = (t < 255) ? s_sc[t + 1] : 0u;
        float runs = (t < 255) ? s_ss[t + 1] : 0.0f;
#pragma unroll
        for (int j = 15; j >= 0; --j) {
            const unsigned int prev = run; const float prevs = runs;
            run += cb[j]; runs += sb[j];
            if (run >= target && prev < target) {
                s_res[0] = (unsigned int)(t * 16 + j); s_res[1] = prev; *s_resf = prevs;
            }
        }
    }
    __syncthreads();
    *c = s_res[0]; *cab = s_res[1]; *sab = *s_resf;
    __syncthreads();
}

// ---------------- K2: fused select chain + finalize. 1 block/image, 1024 threads ----------------
// Scans use 4x uint4 batched loads: 64 B/thread in flight -> latency amortized (round-5 fix).
__global__ __launch_bounds__(1024) void k_tail(
    const unsigned int* __restrict__ keys, const unsigned int* __restrict__ scal,
    const unsigned int* __restrict__ l1c, const float* __restrict__ l1s,
    float* __restrict__ out)
{
    __shared__ unsigned int hc[4096];
    __shared__ float hs[4096];
    __shared__ unsigned int s_sc[256];
    __shared__ float s_ss[256];
    __shared__ unsigned int s_res[2];
    __shared__ float s_resf;

    const int b = blockIdx.x;
    const int tid = threadIdx.x;
    const unsigned int np = scal[b * 16], nn = scal[b * 16 + 1];
    unsigned int k = 0;
    if (np) { const unsigned int kp = np * 3u; k = (kp < nn) ? kp : nn; }
    float s_top = 0.0f;

    if (k > 0) {   // block-uniform (scalar loads)
        // --- level 1: select over global 256-bin hist ---
        if (tid < 256) { s_sc[tid] = l1c[b * 256 + tid]; s_ss[tid] = l1s[b * 256 + tid]; }
        __syncthreads();
        for (int d = 1; d < 256; d <<= 1) {
            unsigned int uc = 0; float fs = 0.0f;
            if (tid < 256) { uc = (tid + d < 256) ? s_sc[tid + d] : 0u; fs = (tid + d < 256) ? s_ss[tid + d] : 0.0f; }
            __syncthreads();
            if (tid < 256) { s_sc[tid] += uc; s_ss[tid] += fs; }
            __syncthreads();
        }
        if (tid < 256) {
            const unsigned int nxt = (tid < 255) ? s_sc[tid + 1] : 0u;
            const float nxs = (tid < 255) ? s_ss[tid + 1] : 0.0f;
            if (s_sc[tid] >= k && nxt < k) { s_res[0] = (unsigned int)tid; s_res[1] = nxt; s_resf = nxs; }
        }
        __syncthreads();
        const unsigned int c1 = s_res[0];
        const unsigned int cab1 = s_res[1];
        const float sab1 = s_resf;
        const unsigned int t2 = k - cab1;
        __syncthreads();

        const uint4* kp4 = (const uint4*)(keys + (size_t)b * NA);

        // --- level 2: 12-bit LDS hist of keys in bin c1 (batched 16 keys/thread/iter) ---
        for (int j = tid; j < 4096; j += 1024) { hc[j] = 0u; hs[j] = 0.0f; }
        __syncthreads();
        for (int base = 0; base < NA4; base += 4096) {
            const int j0 = base + tid, j1 = j0 + 1024, j2 = j0 + 2048, j3 = j0 + 3072;
            uint4 v0 = make_uint4(0,0,0,0), v1 = v0, v2 = v0, v3 = v0;
            if (j0 < NA4) v0 = kp4[j0];
            if (j1 < NA4) v1 = kp4[j1];
            if (j2 < NA4) v2 = kp4[j2];
            if (j3 < NA4) v3 = kp4[j3];
            const unsigned int kk[16] = {v0.x,v0.y,v0.z,v0.w, v1.x,v1.y,v1.z,v1.w,
                                         v2.x,v2.y,v2.z,v2.w, v3.x,v3.y,v3.z,v3.w};
#pragma unroll
            for (int j = 0; j < 16; ++j) {
                const unsigned int key = kk[j];
                if (key && (key >> 24) == c1) {
                    const unsigned int bin = (key >> 12) & 0xfffu;
                    atomicAdd(&hc[bin], 1u);
                    atomicAdd(&hs[bin], key2f(key));
                }
            }
        }
        __syncthreads();
        unsigned int c2, cab2; float sab2;
        sel4096_lds(hc, hs, t2, s_sc, s_ss, s_res, &s_resf, &c2, &cab2, &sab2);
        const unsigned int t3 = t2 - cab2;
        const unsigned int top20 = (c1 << 12) | c2;

        // --- level 3: low-12-bit LDS hist of keys in (c1,c2) ---
        for (int j = tid; j < 4096; j += 1024) { hc[j] = 0u; hs[j] = 0.0f; }
        __syncthreads();
        for (int base = 0; base < NA4; base += 4096) {
            const int j0 = base + tid, j1 = j0 + 1024, j2 = j0 + 2048, j3 = j0 + 3072;
            uint4 v0 = make_uint4(0,0,0,0), v1 = v0, v2 = v0, v3 = v0;
            if (j0 < NA4) v0 = kp4[j0];
            if (j1 < NA4) v1 = kp4[j1];
            if (j2 < NA4) v2 = kp4[j2];
            if (j3 < NA4) v3 = kp4[j3];
            const unsigned int kk[16] = {v0.x,v0.y,v0.z,v0.w, v1.x,v1.y,v1.z,v1.w,
                                         v2.x,v2.y,v2.z,v2.w, v3.x,v3.y,v3.z,v3.w};
#pragma unroll
            for (int j = 0; j < 16; ++j) {
                const unsigned int key = kk[j];
                if (key && (key >> 12) == top20) {
                    const unsigned int bin = key & 0xfffu;
                    atomicAdd(&hc[bin], 1u);
                    atomicAdd(&hs[bin], key2f(key));
                }
            }
        }
        __syncthreads();
        unsigned int c3, cab3; float sab3;
        sel4096_lds(hc, hs, t3, s_sc, s_ss, s_res, &s_resf, &c3, &cab3, &sab3);

        const unsigned int keyv = (c1 << 24) | (c2 << 12) | c3;
        const float v = key2f(keyv);
        const unsigned int rem = t3 - cab3;      // exact tie handling: leaf keys identical
        s_top = sab1 + sab2 + sab3 + (float)rem * v;
    }

    if (tid == 0) {
        float cls_loss = 0.0f, box_loss = 0.0f;
        if (np > 0) {
            const float* fsc = (const float*)(scal + b * 16);
            const float pos_mean = fsc[2] / (float)np;
            const float neg_mean = s_top / (float)((k > 0) ? k : 1u);
            cls_loss = pos_mean + neg_mean;
            box_loss = fsc[3] / (float)(4u * np);
        }
        out[b] = cls_loss;
        out[NB + b] = box_loss;
    }
}

extern "C" void kernel_launch(void* const* d_in, const int* in_sizes, int n_in,
                              void* d_out, int out_size, void* d_ws, size_t ws_size,
                              hipStream_t stream) {
    const float* cls     = (const float*)d_in[0];   // (B, A, 2)
    const float* reg     = (const float*)d_in[1];   // (B, A, 4)
    const float* anchors = (const float*)d_in[2];   // (1, A, 4)
    const float* ann     = (const float*)d_in[3];   // (B, M, 4)
    unsigned int* ws = (unsigned int*)d_ws;
    unsigned int* scal = ws + O_SCAL;
    unsigned int* l1c  = ws + O_L1C;   float* l1s = (float*)(ws + O_L1S);
    unsigned int* keys = ws + O_KEYS;
    (void)in_sizes; (void)n_in; (void)out_size; (void)ws_size;

    hipMemsetAsync(d_ws, 0, (size_t)N_ZERO * 4, stream);
    k_main<<<dim3(CPB, NB), 256,  0, stream>>>(cls, reg, anchors, ann, scal, l1c, l1s, keys);
    k_tail<<<dim3(NB),      1024, 0, stream>>>(keys, scal, l1c, l1s, (float*)d_out);
}